// Round 4
// baseline (257.420 us; speedup 1.0000x reference)
//
#include <hip/hip_runtime.h>

#define FEAT 128
#define HID  128
#define XT_S 33  // 32 + 1 pad: bank (node + k) % 32 -> 2-way across 64 lanes (free)

// ---------------------------------------------------------------------------
// Kernel 1: [A|B] = X @ [W1[:128] | W1[128:]]  (N x 256 concat, fp32)
// R1-R3 post-mortem: any scheme where each wave re-reads the wave-uniform W
// operand from LDS is DS-slot-bound (4 waves x 4 b128/k = ~192 cyc of the
// CU's single LDS pipe per k vs 64 cyc VALU -> 27-37% VALUBusy, measured
// thrice). Fix: W goes through the SCALAR path (s_load -> SGPR -> v_fmac
// with SGPR src0), which costs zero DS/VALU slots. X is batched from LDS
// into VGPRs once per kc (32 x b32, 2-way banks, one drain), so the k-loop
// is pure SMEM + FMA: per k-pair, 4 uniform float4-quad loads (s_load) and
// 64 FMAs; full unroll lets the scheduler hoist the next pair's s_loads
// over the current FMAs (~64-SGPR window) to cover SMEM latency, and ~6
// waves/SIMD of TLP (VGPR ~80, LDS 8.5 KB) hides the rest.
// Layout: block = 64 nodes x one 128-col half (A or B); wave = 32 uniform
// cols (readfirstlane'd) x 64 nodes (lane = node). Grid 2*ceil(N/64)=1564,
// bijective XCD-chunked swizzle keeps the A/B blocks of one X-tile on one
// XCD (13 MB FETCH verified in R1-R3). b1 folded into the A-half epilogue.
// ---------------------------------------------------------------------------
__global__ __launch_bounds__(256) void gemm_ab(
    const float* __restrict__ X, const float* __restrict__ W1,
    const float* __restrict__ b1, float* __restrict__ A,
    float* __restrict__ B, int N) {
  __shared__ float xs[64 * XT_S];  // xs[node][k_local], 8.45 KB
  const int t = threadIdx.x;

  // bijective chunked XCD swizzle (nb need not be %8==0)
  const int nb = gridDim.x;
  const int q = nb >> 3, r = nb & 7;
  const int xcd = blockIdx.x & 7, bidx = blockIdx.x >> 3;
  const int nw = (xcd < r ? xcd * (q + 1) : r * (q + 1) + (xcd - r) * q) + bidx;
  const int n0 = (nw >> 1) * 64;
  const int isA = (nw & 1) == 0;
  const float* Wb = W1 + (isA ? 0 : (size_t)128 * HID);
  float* Obase = isA ? A : B;

  const int l = t & 63;  // lane = node n0 + l
  // wave-uniform col base within the half -> scalar W loads
  const int cb = __builtin_amdgcn_readfirstlane((t >> 6) * 32);

  float acc[32];
#pragma unroll
  for (int c = 0; c < 32; ++c) acc[c] = 0.f;

  for (int kc = 0; kc < 4; ++kc) {
    __syncthreads();
    // stage X chunk, natural row layout: xs[node][k_local]. 8 lanes/node ->
    // 128 B contiguous per 8 lanes (coalesced); b32 stores, ~2-way banks.
#pragma unroll
    for (int rep = 0; rep < 2; ++rep) {
      const int idx = rep * 256 + t;   // 0..511 float4s
      const int nl = idx >> 3;         // 0..63
      const int qd = (idx & 7) * 4;    // 0..28
      const int n = n0 + nl;
      float4 v = make_float4(0.f, 0.f, 0.f, 0.f);
      if (n < N) v = *(const float4*)(X + (size_t)n * FEAT + kc * 32 + qd);
      xs[nl * XT_S + qd + 0] = v.x;
      xs[nl * XT_S + qd + 1] = v.y;
      xs[nl * XT_S + qd + 2] = v.z;
      xs[nl * XT_S + qd + 3] = v.w;
    }
    __syncthreads();

    // batch X into registers: one drain, then the k-loop is LDS-free
    float xr[32];
#pragma unroll
    for (int j = 0; j < 32; ++j) xr[j] = xs[l * XT_S + j];

#pragma unroll
    for (int k = 0; k < 32; k += 2) {
      const float* w0p = Wb + (size_t)(kc * 32 + k) * HID + cb;  // uniform
      const float* w1p = w0p + HID;
      float wv0[32], wv1[32];
#pragma unroll
      for (int c4 = 0; c4 < 8; ++c4) {
        *(float4*)&wv0[c4 * 4] = *(const float4*)(w0p + c4 * 4);
        *(float4*)&wv1[c4 * 4] = *(const float4*)(w1p + c4 * 4);
      }
#pragma unroll
      for (int c = 0; c < 32; ++c) acc[c] = fmaf(xr[k], wv0[c], acc[c]);
#pragma unroll
      for (int c = 0; c < 32; ++c) acc[c] = fmaf(xr[k + 1], wv1[c], acc[c]);
    }
  }

  // epilogue: fold b1 into the A-half so edge_z needn't read it
  float bb[32];
#pragma unroll
  for (int c = 0; c < 32; ++c) bb[c] = 0.f;
  if (isA) {
#pragma unroll
    for (int c4 = 0; c4 < 8; ++c4)
      *(float4*)&bb[c4 * 4] = *(const float4*)(b1 + cb + c4 * 4);
  }
  const int n = n0 + l;
  if (n < N) {
    float* o = Obase + (size_t)n * HID + cb;
#pragma unroll
    for (int c4 = 0; c4 < 8; ++c4)
      *(float4*)(o + c4 * 4) = make_float4(
          acc[c4 * 4 + 0] + bb[c4 * 4 + 0], acc[c4 * 4 + 1] + bb[c4 * 4 + 1],
          acc[c4 * 4 + 2] + bb[c4 * 4 + 2], acc[c4 * 4 + 3] + bb[c4 * 4 + 3]);
  }
}

// ---------------------------------------------------------------------------
// Kernel 2: CSR row offsets from sorted src via binary search. rs has N+1 ents.
// ---------------------------------------------------------------------------
__global__ __launch_bounds__(256) void row_offsets(
    const int* __restrict__ src, int* __restrict__ rs, int N, int E) {
  const int n = blockIdx.x * 256 + threadIdx.x;
  if (n > N) return;
  int lo = 0, hi = E;
  while (lo < hi) {
    const int mid = (lo + hi) >> 1;
    if (src[mid] < n) lo = mid + 1; else hi = mid;
  }
  rs[n] = lo;
}

// ---------------------------------------------------------------------------
// Kernel 3: z[e] = W2 . relu(A[src[e]] + B[dst[e]]) + b2   (b1 pre-folded in A)
// 16 lanes per edge (8 floats/lane), 2 edges per 16-lane group, all 8 row
// loads issued before any reduce. 4-step shfl_xor reduce.
// ---------------------------------------------------------------------------
__global__ __launch_bounds__(256) void edge_z(
    const float* __restrict__ A, const float* __restrict__ B,
    const float* __restrict__ W2, const float* __restrict__ b2,
    const int* __restrict__ src, const int* __restrict__ dst,
    float* __restrict__ z, int E) {
  const int g = threadIdx.x >> 4;
  const int l = threadIdx.x & 15;
  const int e0 = blockIdx.x * 32 + g * 2;
  if (e0 >= E) return;
  const int e1 = e0 + 1;
  const bool has1 = e1 < E;

  const int u0 = src[e0], v0 = dst[e0];
  const int u1 = has1 ? src[e1] : u0;
  const int v1 = has1 ? dst[e1] : v0;

  const float4* Au0 = (const float4*)(A + (size_t)u0 * HID) + l * 2;
  const float4* Bv0 = (const float4*)(B + (size_t)v0 * HID) + l * 2;
  const float4* Au1 = (const float4*)(A + (size_t)u1 * HID) + l * 2;
  const float4* Bv1 = (const float4*)(B + (size_t)v1 * HID) + l * 2;

  const float4 a00 = Au0[0], a01 = Au0[1];
  const float4 b00 = Bv0[0], b01 = Bv0[1];
  const float4 a10 = Au1[0], a11 = Au1[1];
  const float4 b10 = Bv1[0], b11 = Bv1[1];

  const float4 w0 = *(const float4*)(W2 + l * 8);
  const float4 w1 = *(const float4*)(W2 + l * 8 + 4);
  const float bias2 = b2[0];

  float p0 = fmaxf(a00.x + b00.x, 0.f) * w0.x
           + fmaxf(a00.y + b00.y, 0.f) * w0.y
           + fmaxf(a00.z + b00.z, 0.f) * w0.z
           + fmaxf(a00.w + b00.w, 0.f) * w0.w
           + fmaxf(a01.x + b01.x, 0.f) * w1.x
           + fmaxf(a01.y + b01.y, 0.f) * w1.y
           + fmaxf(a01.z + b01.z, 0.f) * w1.z
           + fmaxf(a01.w + b01.w, 0.f) * w1.w;
  float p1 = fmaxf(a10.x + b10.x, 0.f) * w0.x
           + fmaxf(a10.y + b10.y, 0.f) * w0.y
           + fmaxf(a10.z + b10.z, 0.f) * w0.z
           + fmaxf(a10.w + b10.w, 0.f) * w0.w
           + fmaxf(a11.x + b11.x, 0.f) * w1.x
           + fmaxf(a11.y + b11.y, 0.f) * w1.y
           + fmaxf(a11.z + b11.z, 0.f) * w1.z
           + fmaxf(a11.w + b11.w, 0.f) * w1.w;

#pragma unroll
  for (int m = 8; m >= 1; m >>= 1) {
    p0 += __shfl_xor(p0, m);
    p1 += __shfl_xor(p1, m);
  }
  if (l == 0) {
    z[e0] = p0 + bias2;
    if (has1) z[e1] = p1 + bias2;
  }
}

// ---------------------------------------------------------------------------
// Kernel 4: per-node log-softmax + K Gumbel rounds. FOUR nodes per wave:
// 16 lanes per node, 2 edges per lane (covers deg<=32; avg deg 16). 4-step
// shfl_xor reduces serve 4 nodes per DS instruction. Works in ex = exp(s)
// space: argmax(ex) == argmax(s); fast __logf/__expf.
// ---------------------------------------------------------------------------
__global__ __launch_bounds__(256) void seg_sample(
    const float* __restrict__ z, const float* __restrict__ U,
    const int* __restrict__ dst, const int* __restrict__ rs,
    float* __restrict__ out_sel, float* __restrict__ out_soft,
    int N, int E, int K) {
  const int t = threadIdx.x;
  const int lane = t & 63;
  const int qtr = lane >> 4;   // quarter 0..3: one node each
  const int ql = lane & 15;    // lane within node: edges 2*ql, 2*ql+1
  const int n = blockIdx.x * 16 + (t >> 6) * 4 + qtr;
  const float INVTAU = 1.0f / 0.9991f;

  int start = 0, deg = 0;
  if (n < N) { start = rs[n]; deg = rs[n + 1] - start; }

  if (__all(deg <= 32)) {
    // ---- fast path: 16-lane quarter per node, 2 edges/lane ----
    if (n >= N) return;
    if (deg == 0) {
      if (ql == 0)
        for (int k = 0; k < K; ++k) out_sel[(size_t)k * N + n] = -2147483648.0f;
      return;
    }
    const bool a0 = 2 * ql < deg;
    const bool a1 = 2 * ql + 1 < deg;
    const int e0 = start + 2 * ql;
    const int e1 = e0 + 1;
    const float z0 = a0 ? z[e0] : -INFINITY;
    const float z1 = a1 ? z[e1] : -INFINITY;
    const int d0 = a0 ? dst[e0] : -1;
    const int d1 = a1 ? dst[e1] : -1;

    float zmax = fmaxf(z0, z1);
#pragma unroll
    for (int m = 8; m >= 1; m >>= 1) zmax = fmaxf(zmax, __shfl_xor(zmax, m));
    float den = (a0 ? __expf(z0 - zmax) : 0.f) + (a1 ? __expf(z1 - zmax) : 0.f);
#pragma unroll
    for (int m = 8; m >= 1; m >>= 1) den += __shfl_xor(den, m);
    const float logd = __logf(den);
    const float lp0 = (z0 - zmax) - logd;  // per-edge log-prob
    const float lp1 = (z1 - zmax) - logd;

    for (int k = 0; k < K; ++k) {
      float ex0 = 0.f, ex1 = 0.f;
      if (a0) {
        const float uu = U[(size_t)k * E + e0];
        const float gum = -__logf(-__logf(uu));
        ex0 = __expf((lp0 + gum) * INVTAU);  // exp(s); s in [-19,15] -> safe
      }
      if (a1) {
        const float uu = U[(size_t)k * E + e1];
        const float gum = -__logf(-__logf(uu));
        ex1 = __expf((lp1 + gum) * INVTAU);
      }
      // lane-local pair combine (tie -> larger dst, matching reference)
      float d2 = ex0 + ex1;
      float mx;
      int md;
      if (ex1 > ex0)      { mx = ex1; md = d1; }
      else if (ex1 < ex0) { mx = ex0; md = d0; }
      else                { mx = ex0; md = max(d0, d1); }
#pragma unroll
      for (int m = 8; m >= 1; m >>= 1) {
        d2 += __shfl_xor(d2, m);
        const float ox = __shfl_xor(mx, m);
        const int od = __shfl_xor(md, m);
        if (ox > mx) { mx = ox; md = od; }
        else if (ox == mx) md = max(md, od);
      }
      if (ql == 0) out_sel[(size_t)k * N + n] = (float)md;
      const float inv = __builtin_amdgcn_rcpf(d2);
      if (a0) out_soft[(size_t)k * E + e0] = ex0 * inv;
      if (a1) out_soft[(size_t)k * E + e1] = ex1 * inv;
    }
    return;
  }

  // ---- general path (some deg > 32, ~5 nodes): full wave per node, x4 ----
  const int wbase = blockIdx.x * 16 + (t >> 6) * 4;
  for (int j = 0; j < 4; ++j) {
    const int nn = wbase + j;
    if (nn >= N) continue;
    const int st = rs[nn];
    const int dg = rs[nn + 1] - st;
    if (dg == 0) {
      if (lane == 0)
        for (int k = 0; k < K; ++k) out_sel[(size_t)k * N + nn] = -2147483648.0f;
      continue;
    }
    float zmax = -INFINITY;
    for (int c = lane; c < dg; c += 64) zmax = fmaxf(zmax, z[st + c]);
#pragma unroll
    for (int m = 32; m >= 1; m >>= 1) zmax = fmaxf(zmax, __shfl_xor(zmax, m));
    float den = 0.f;
    for (int c = lane; c < dg; c += 64) den += expf(z[st + c] - zmax);
#pragma unroll
    for (int m = 32; m >= 1; m >>= 1) den += __shfl_xor(den, m);
    const float logd = logf(den);

    for (int k = 0; k < K; ++k) {
      float m2 = -INFINITY;
      for (int c = lane; c < dg; c += 64) {
        const int e = st + c;
        const float gum = -logf(-logf(U[(size_t)k * E + e]));
        const float s = ((z[e] - zmax) - logd + gum) * INVTAU;
        m2 = fmaxf(m2, s);
      }
#pragma unroll
      for (int m = 32; m >= 1; m >>= 1) m2 = fmaxf(m2, __shfl_xor(m2, m));
      float d2 = 0.f;
      int cand = -1;
      for (int c = lane; c < dg; c += 64) {
        const int e = st + c;
        const float gum = -logf(-logf(U[(size_t)k * E + e]));
        const float s = ((z[e] - zmax) - logd + gum) * INVTAU;
        d2 += expf(s - m2);
        if (s >= m2) cand = max(cand, dst[e]);
      }
#pragma unroll
      for (int m = 32; m >= 1; m >>= 1) d2 += __shfl_xor(d2, m);
#pragma unroll
      for (int m = 32; m >= 1; m >>= 1) cand = max(cand, __shfl_xor(cand, m));
      if (lane == 0) out_sel[(size_t)k * N + nn] = (float)cand;
      for (int c = lane; c < dg; c += 64) {
        const int e = st + c;
        const float gum = -logf(-logf(U[(size_t)k * E + e]));
        const float s = ((z[e] - zmax) - logd + gum) * INVTAU;
        out_soft[(size_t)k * E + e] = expf(s - m2) / d2;
      }
    }
  }
}

// ---------------------------------------------------------------------------
extern "C" void kernel_launch(void* const* d_in, const int* in_sizes, int n_in,
                              void* d_out, int out_size, void* d_ws, size_t ws_size,
                              hipStream_t stream) {
  const float* X  = (const float*)d_in[0];  // (N, 128)
  const float* W1 = (const float*)d_in[1];  // (256, 128)
  const float* b1 = (const float*)d_in[2];  // (128,)
  const float* W2 = (const float*)d_in[3];  // (128,)
  const float* b2 = (const float*)d_in[4];  // (1,)
  const float* U  = (const float*)d_in[5];  // (K, E)
  const int* src  = (const int*)d_in[6];    // (E,) sorted
  const int* dst  = (const int*)d_in[7];    // (E,)
  const int E = in_sizes[6];
  const int K = in_sizes[5] / E;
  const int N = in_sizes[0] / FEAT;

  // workspace: A (N*128 f32) | B (N*128 f32) | z (E f32) | rs (N+1 i32)
  float* A = (float*)d_ws;
  float* B = A + (size_t)N * HID;
  float* z = B + (size_t)N * HID;
  int* rs  = (int*)(z + E);

  float* out_sel  = (float*)d_out;                  // (K, N) as f32
  float* out_soft = (float*)d_out + (size_t)K * N;  // (K, E)

  hipLaunchKernelGGL(gemm_ab, dim3(2 * ((N + 63) / 64)), dim3(256), 0, stream,
                     X, W1, b1, A, B, N);
  hipLaunchKernelGGL(row_offsets, dim3((N + 256) / 256), dim3(256), 0, stream,
                     src, rs, N, E);
  hipLaunchKernelGGL(edge_z, dim3((E + 31) / 32), dim3(256), 0, stream,
                     A, B, W2, b2, src, dst, z, E);
  hipLaunchKernelGGL(seg_sample, dim3((N + 15) / 16), dim3(256), 0, stream,
                     z, U, dst, rs, out_sel, out_soft, N, E, K);
}

// Round 5
// 254.997 us; speedup vs baseline: 1.0095x; 1.0095x over previous
//
#include <hip/hip_runtime.h>

#define FEAT 128
#define HID  128
#define XS_S 132  // 128 + 4 pad; multiple of 4 keeps b128 alignment on xs rows

// ---------------------------------------------------------------------------
// Kernel 1: [A|B] = X @ [W1[:128] | W1[128:]]  (N x 256 concat, fp32)
// R1-R4 post-mortem: the CU's SINGLE LDS pipe serves 4 SIMDs, so a lane
// micro-tile m x n (2mn VALU-cyc vs ~3(m+n) DS-cyc) needs mn >= 6(m+n) to
// keep VALU fed. Old 4x8 = 44% ceiling (R0 ~60us); R3's 2x16-broadcast =
// 27%; scalar-W paths (R2/R4) die on SMEM serialization. This version: 8x8
// micro-tile -> 64 FMA-insts (128 cyc) vs 4 b128 (48 DS-cyc) per lane-k ->
// 4x48=192 vs 128 -> 66% VALU ceiling, ~2x the R0 structure.
// Wave = 64 nodes x 64 cols (lane grid 8 node-grp x 8 col-grp); block =
// 2 waves = 128 nodes x 64 cols (128 threads). ws reads are 8-lane
// broadcasts at 2-way banks; xs b128 reads 2-way. LDS 24.6 KB -> 6
// blocks/CU = 3 waves/SIMD TLP over the pure-DS k-loop (fine-grained
// lgkmcnt pipelining, verified R3). Grid 1564, bijective XCD-chunked
// swizzle keeps the 4 col-group blocks of one X-tile on one XCD (13 MB
// FETCH verified R1-R4). b1 folded into the A-half epilogue.
// ---------------------------------------------------------------------------
__global__ __launch_bounds__(128) void gemm_ab(
    const float* __restrict__ X, const float* __restrict__ W1,
    const float* __restrict__ b1, float* __restrict__ A,
    float* __restrict__ B, int N) {
  __shared__ float xs[32 * XS_S];  // xs[k_local][node], 16.9 KB
  __shared__ float ws[32 * 64];    // ws[k_local][col],   8 KB
  const int t = threadIdx.x;  // 0..127

  // bijective chunked XCD swizzle (nb need not be %8==0)
  const int nb = gridDim.x;
  const int q = nb >> 3, r = nb & 7;
  const int xcd = blockIdx.x & 7, bidx = blockIdx.x >> 3;
  const int nw = (xcd < r ? xcd * (q + 1) : r * (q + 1) + (xcd - r) * q) + bidx;
  const int n0 = (nw >> 2) * 128;
  const int jb = (nw & 3) * 64;   // concat col base: 0,64 -> A ; 128,192 -> B
  const int isA = jb < 128;
  const int ob = jb & 127;        // 0 or 64 within the half
  const float* Wb = W1 + (isA ? 0 : (size_t)128 * HID) + ob;
  float* Obase = (isA ? A : B) + ob;

  const int l = t & 63;
  const int w = t >> 6;       // wave 0/1 -> nodes w*64 ..
  const int ng = l & 7;       // node group: nodes w*64 + ng*8 .. +7
  const int cg = l >> 3;      // col group:  cols cg*8 .. +7

  float acc[8][8];
#pragma unroll
  for (int rr = 0; rr < 8; ++rr)
#pragma unroll
    for (int c = 0; c < 8; ++c) acc[rr][c] = 0.f;

  for (int kc = 0; kc < 4; ++kc) {
    __syncthreads();
    // stage X chunk transposed: xs[k_local][node]. 8 threads/node row ->
    // coalesced 128-B global reads; b32 scatter stores (~2-way banks).
#pragma unroll
    for (int rep = 0; rep < 8; ++rep) {
      const int idx = rep * 128 + t;   // 0..1023 float4s
      const int nl = idx >> 3;         // 0..127
      const int qd = (idx & 7) * 4;    // 0..28
      const int n = n0 + nl;
      float4 v = make_float4(0.f, 0.f, 0.f, 0.f);
      if (n < N) v = *(const float4*)(X + (size_t)n * FEAT + kc * 32 + qd);
      xs[(qd + 0) * XS_S + nl] = v.x;
      xs[(qd + 1) * XS_S + nl] = v.y;
      xs[(qd + 2) * XS_S + nl] = v.z;
      xs[(qd + 3) * XS_S + nl] = v.w;
    }
    // stage W chunk: ws[k_local][col] (32 x 64 floats = 512 float4s)
#pragma unroll
    for (int rep = 0; rep < 4; ++rep) {
      const int idx = rep * 128 + t;   // 0..511 float4s
      const int wr = idx >> 4;         // 0..31 (k_local)
      const int c4 = (idx & 15) * 4;   // 0..60
      *(float4*)&ws[wr * 64 + c4] =
          *(const float4*)(Wb + (size_t)(kc * 32 + wr) * HID + c4);
    }
    __syncthreads();

#pragma unroll 8
    for (int k = 0; k < 32; ++k) {
      const float4 x0 = *(const float4*)&xs[k * XS_S + w * 64 + ng * 8];
      const float4 x1 = *(const float4*)&xs[k * XS_S + w * 64 + ng * 8 + 4];
      const float4 w0 = *(const float4*)&ws[k * 64 + cg * 8];
      const float4 w1 = *(const float4*)&ws[k * 64 + cg * 8 + 4];
      const float xr[8] = {x0.x, x0.y, x0.z, x0.w, x1.x, x1.y, x1.z, x1.w};
      const float wc[8] = {w0.x, w0.y, w0.z, w0.w, w1.x, w1.y, w1.z, w1.w};
#pragma unroll
      for (int rr = 0; rr < 8; ++rr)
#pragma unroll
        for (int c = 0; c < 8; ++c)
          acc[rr][c] = fmaf(xr[rr], wc[c], acc[rr][c]);
    }
  }

  // epilogue: fold b1 into the A-half so edge_z needn't read it
  float bb[8];
#pragma unroll
  for (int c = 0; c < 8; ++c) bb[c] = 0.f;
  if (isA) {
    *(float4*)&bb[0] = *(const float4*)(b1 + ob + cg * 8);
    *(float4*)&bb[4] = *(const float4*)(b1 + ob + cg * 8 + 4);
  }
#pragma unroll
  for (int rr = 0; rr < 8; ++rr) {
    const int n = n0 + w * 64 + ng * 8 + rr;
    if (n < N) {
      float* o = Obase + (size_t)n * HID + cg * 8;
      *(float4*)o = make_float4(acc[rr][0] + bb[0], acc[rr][1] + bb[1],
                                acc[rr][2] + bb[2], acc[rr][3] + bb[3]);
      *(float4*)(o + 4) = make_float4(acc[rr][4] + bb[4], acc[rr][5] + bb[5],
                                      acc[rr][6] + bb[6], acc[rr][7] + bb[7]);
    }
  }
}

// ---------------------------------------------------------------------------
// Kernel 2: CSR row offsets from sorted src via binary search. rs has N+1 ents.
// ---------------------------------------------------------------------------
__global__ __launch_bounds__(256) void row_offsets(
    const int* __restrict__ src, int* __restrict__ rs, int N, int E) {
  const int n = blockIdx.x * 256 + threadIdx.x;
  if (n > N) return;
  int lo = 0, hi = E;
  while (lo < hi) {
    const int mid = (lo + hi) >> 1;
    if (src[mid] < n) lo = mid + 1; else hi = mid;
  }
  rs[n] = lo;
}

// ---------------------------------------------------------------------------
// Kernel 3: z[e] = W2 . relu(A[src[e]] + B[dst[e]]) + b2   (b1 pre-folded in A)
// 16 lanes per edge (8 floats/lane), 2 edges per 16-lane group, all 8 row
// loads issued before any reduce. 4-step shfl_xor reduce.
// ---------------------------------------------------------------------------
__global__ __launch_bounds__(256) void edge_z(
    const float* __restrict__ A, const float* __restrict__ B,
    const float* __restrict__ W2, const float* __restrict__ b2,
    const int* __restrict__ src, const int* __restrict__ dst,
    float* __restrict__ z, int E) {
  const int g = threadIdx.x >> 4;
  const int l = threadIdx.x & 15;
  const int e0 = blockIdx.x * 32 + g * 2;
  if (e0 >= E) return;
  const int e1 = e0 + 1;
  const bool has1 = e1 < E;

  const int u0 = src[e0], v0 = dst[e0];
  const int u1 = has1 ? src[e1] : u0;
  const int v1 = has1 ? dst[e1] : v0;

  const float4* Au0 = (const float4*)(A + (size_t)u0 * HID) + l * 2;
  const float4* Bv0 = (const float4*)(B + (size_t)v0 * HID) + l * 2;
  const float4* Au1 = (const float4*)(A + (size_t)u1 * HID) + l * 2;
  const float4* Bv1 = (const float4*)(B + (size_t)v1 * HID) + l * 2;

  const float4 a00 = Au0[0], a01 = Au0[1];
  const float4 b00 = Bv0[0], b01 = Bv0[1];
  const float4 a10 = Au1[0], a11 = Au1[1];
  const float4 b10 = Bv1[0], b11 = Bv1[1];

  const float4 w0 = *(const float4*)(W2 + l * 8);
  const float4 w1 = *(const float4*)(W2 + l * 8 + 4);
  const float bias2 = b2[0];

  float p0 = fmaxf(a00.x + b00.x, 0.f) * w0.x
           + fmaxf(a00.y + b00.y, 0.f) * w0.y
           + fmaxf(a00.z + b00.z, 0.f) * w0.z
           + fmaxf(a00.w + b00.w, 0.f) * w0.w
           + fmaxf(a01.x + b01.x, 0.f) * w1.x
           + fmaxf(a01.y + b01.y, 0.f) * w1.y
           + fmaxf(a01.z + b01.z, 0.f) * w1.z
           + fmaxf(a01.w + b01.w, 0.f) * w1.w;
  float p1 = fmaxf(a10.x + b10.x, 0.f) * w0.x
           + fmaxf(a10.y + b10.y, 0.f) * w0.y
           + fmaxf(a10.z + b10.z, 0.f) * w0.z
           + fmaxf(a10.w + b10.w, 0.f) * w0.w
           + fmaxf(a11.x + b11.x, 0.f) * w1.x
           + fmaxf(a11.y + b11.y, 0.f) * w1.y
           + fmaxf(a11.z + b11.z, 0.f) * w1.z
           + fmaxf(a11.w + b11.w, 0.f) * w1.w;

#pragma unroll
  for (int m = 8; m >= 1; m >>= 1) {
    p0 += __shfl_xor(p0, m);
    p1 += __shfl_xor(p1, m);
  }
  if (l == 0) {
    z[e0] = p0 + bias2;
    if (has1) z[e1] = p1 + bias2;
  }
}

// ---------------------------------------------------------------------------
// Kernel 4: per-node log-softmax + K Gumbel rounds. FOUR nodes per wave:
// 16 lanes per node, 2 edges per lane (covers deg<=32; avg deg 16). 4-step
// shfl_xor reduces serve 4 nodes per DS instruction. Works in ex = exp(s)
// space: argmax(ex) == argmax(s); fast __logf/__expf.
// ---------------------------------------------------------------------------
__global__ __launch_bounds__(256) void seg_sample(
    const float* __restrict__ z, const float* __restrict__ U,
    const int* __restrict__ dst, const int* __restrict__ rs,
    float* __restrict__ out_sel, float* __restrict__ out_soft,
    int N, int E, int K) {
  const int t = threadIdx.x;
  const int lane = t & 63;
  const int qtr = lane >> 4;   // quarter 0..3: one node each
  const int ql = lane & 15;    // lane within node: edges 2*ql, 2*ql+1
  const int n = blockIdx.x * 16 + (t >> 6) * 4 + qtr;
  const float INVTAU = 1.0f / 0.9991f;

  int start = 0, deg = 0;
  if (n < N) { start = rs[n]; deg = rs[n + 1] - start; }

  if (__all(deg <= 32)) {
    // ---- fast path: 16-lane quarter per node, 2 edges/lane ----
    if (n >= N) return;
    if (deg == 0) {
      if (ql == 0)
        for (int k = 0; k < K; ++k) out_sel[(size_t)k * N + n] = -2147483648.0f;
      return;
    }
    const bool a0 = 2 * ql < deg;
    const bool a1 = 2 * ql + 1 < deg;
    const int e0 = start + 2 * ql;
    const int e1 = e0 + 1;
    const float z0 = a0 ? z[e0] : -INFINITY;
    const float z1 = a1 ? z[e1] : -INFINITY;
    const int d0 = a0 ? dst[e0] : -1;
    const int d1 = a1 ? dst[e1] : -1;

    float zmax = fmaxf(z0, z1);
#pragma unroll
    for (int m = 8; m >= 1; m >>= 1) zmax = fmaxf(zmax, __shfl_xor(zmax, m));
    float den = (a0 ? __expf(z0 - zmax) : 0.f) + (a1 ? __expf(z1 - zmax) : 0.f);
#pragma unroll
    for (int m = 8; m >= 1; m >>= 1) den += __shfl_xor(den, m);
    const float logd = __logf(den);
    const float lp0 = (z0 - zmax) - logd;  // per-edge log-prob
    const float lp1 = (z1 - zmax) - logd;

    for (int k = 0; k < K; ++k) {
      float ex0 = 0.f, ex1 = 0.f;
      if (a0) {
        const float uu = U[(size_t)k * E + e0];
        const float gum = -__logf(-__logf(uu));
        ex0 = __expf((lp0 + gum) * INVTAU);  // exp(s); s in [-19,15] -> safe
      }
      if (a1) {
        const float uu = U[(size_t)k * E + e1];
        const float gum = -__logf(-__logf(uu));
        ex1 = __expf((lp1 + gum) * INVTAU);
      }
      // lane-local pair combine (tie -> larger dst, matching reference)
      float d2 = ex0 + ex1;
      float mx;
      int md;
      if (ex1 > ex0)      { mx = ex1; md = d1; }
      else if (ex1 < ex0) { mx = ex0; md = d0; }
      else                { mx = ex0; md = max(d0, d1); }
#pragma unroll
      for (int m = 8; m >= 1; m >>= 1) {
        d2 += __shfl_xor(d2, m);
        const float ox = __shfl_xor(mx, m);
        const int od = __shfl_xor(md, m);
        if (ox > mx) { mx = ox; md = od; }
        else if (ox == mx) md = max(md, od);
      }
      if (ql == 0) out_sel[(size_t)k * N + n] = (float)md;
      const float inv = __builtin_amdgcn_rcpf(d2);
      if (a0) out_soft[(size_t)k * E + e0] = ex0 * inv;
      if (a1) out_soft[(size_t)k * E + e1] = ex1 * inv;
    }
    return;
  }

  // ---- general path (some deg > 32, ~5 nodes): full wave per node, x4 ----
  const int wbase = blockIdx.x * 16 + (t >> 6) * 4;
  for (int j = 0; j < 4; ++j) {
    const int nn = wbase + j;
    if (nn >= N) continue;
    const int st = rs[nn];
    const int dg = rs[nn + 1] - st;
    if (dg == 0) {
      if (lane == 0)
        for (int k = 0; k < K; ++k) out_sel[(size_t)k * N + nn] = -2147483648.0f;
      continue;
    }
    float zmax = -INFINITY;
    for (int c = lane; c < dg; c += 64) zmax = fmaxf(zmax, z[st + c]);
#pragma unroll
    for (int m = 32; m >= 1; m >>= 1) zmax = fmaxf(zmax, __shfl_xor(zmax, m));
    float den = 0.f;
    for (int c = lane; c < dg; c += 64) den += expf(z[st + c] - zmax);
#pragma unroll
    for (int m = 32; m >= 1; m >>= 1) den += __shfl_xor(den, m);
    const float logd = logf(den);

    for (int k = 0; k < K; ++k) {
      float m2 = -INFINITY;
      for (int c = lane; c < dg; c += 64) {
        const int e = st + c;
        const float gum = -logf(-logf(U[(size_t)k * E + e]));
        const float s = ((z[e] - zmax) - logd + gum) * INVTAU;
        m2 = fmaxf(m2, s);
      }
#pragma unroll
      for (int m = 32; m >= 1; m >>= 1) m2 = fmaxf(m2, __shfl_xor(m2, m));
      float d2 = 0.f;
      int cand = -1;
      for (int c = lane; c < dg; c += 64) {
        const int e = st + c;
        const float gum = -logf(-logf(U[(size_t)k * E + e]));
        const float s = ((z[e] - zmax) - logd + gum) * INVTAU;
        d2 += expf(s - m2);
        if (s >= m2) cand = max(cand, dst[e]);
      }
#pragma unroll
      for (int m = 32; m >= 1; m >>= 1) d2 += __shfl_xor(d2, m);
#pragma unroll
      for (int m = 32; m >= 1; m >>= 1) cand = max(cand, __shfl_xor(cand, m));
      if (lane == 0) out_sel[(size_t)k * N + nn] = (float)cand;
      for (int c = lane; c < dg; c += 64) {
        const int e = st + c;
        const float gum = -logf(-logf(U[(size_t)k * E + e]));
        const float s = ((z[e] - zmax) - logd + gum) * INVTAU;
        out_soft[(size_t)k * E + e] = expf(s - m2) / d2;
      }
    }
  }
}

// ---------------------------------------------------------------------------
extern "C" void kernel_launch(void* const* d_in, const int* in_sizes, int n_in,
                              void* d_out, int out_size, void* d_ws, size_t ws_size,
                              hipStream_t stream) {
  const float* X  = (const float*)d_in[0];  // (N, 128)
  const float* W1 = (const float*)d_in[1];  // (256, 128)
  const float* b1 = (const float*)d_in[2];  // (128,)
  const float* W2 = (const float*)d_in[3];  // (128,)
  const float* b2 = (const float*)d_in[4];  // (1,)
  const float* U  = (const float*)d_in[5];  // (K, E)
  const int* src  = (const int*)d_in[6];    // (E,) sorted
  const int* dst  = (const int*)d_in[7];    // (E,)
  const int E = in_sizes[6];
  const int K = in_sizes[5] / E;
  const int N = in_sizes[0] / FEAT;

  // workspace: A (N*128 f32) | B (N*128 f32) | z (E f32) | rs (N+1 i32)
  float* A = (float*)d_ws;
  float* B = A + (size_t)N * HID;
  float* z = B + (size_t)N * HID;
  int* rs  = (int*)(z + E);

  float* out_sel  = (float*)d_out;                  // (K, N) as f32
  float* out_soft = (float*)d_out + (size_t)K * N;  // (K, E)

  hipLaunchKernelGGL(gemm_ab, dim3(4 * ((N + 127) / 128)), dim3(128), 0, stream,
                     X, W1, b1, A, B, N);
  hipLaunchKernelGGL(row_offsets, dim3((N + 256) / 256), dim3(256), 0, stream,
                     src, rs, N, E);
  hipLaunchKernelGGL(edge_z, dim3((E + 31) / 32), dim3(256), 0, stream,
                     A, B, W2, b2, src, dst, z, E);
  hipLaunchKernelGGL(seg_sample, dim3((N + 15) / 16), dim3(256), 0, stream,
                     z, U, dst, rs, out_sel, out_soft, N, E, K);
}

// Round 7
// 237.978 us; speedup vs baseline: 1.0817x; 1.0715x over previous
//
#include <hip/hip_runtime.h>

#define FEAT 128
#define HID  128
#define XS_S 132   // 128 nodes + 4 pad; multiple of 4 keeps b128 alignment
#define MAXE 2048  // per-block edge capacity: 16 nodes, mean 256 edges, >100 sigma headroom

// ---------------------------------------------------------------------------
// Kernel 1: [A|B] = X @ [W1[:128] | W1[128:]]  (N x 256 concat, fp32)
// Round-0 measured-best structure (<=57.6us): 256 threads, 128 nodes x 64
// concat-cols, 4x8 micro-tile, 25 KB LDS -> 6 blocks/CU = 24 waves/CU TLP
// (R1-R5: every "better DS-ratio" restructure lost on latency-hiding TLP;
// VALU-active is pinned at the ~21us FMA floor in ALL variants).
// Kept (verified R1-R5): bijective XCD-chunked swizzle (FETCH pinned at
// ~13 MB) and b1 folded into the A-half epilogue.
// ---------------------------------------------------------------------------
__global__ __launch_bounds__(256) void gemm_ab(
    const float* __restrict__ X, const float* __restrict__ W1,
    const float* __restrict__ b1, float* __restrict__ A,
    float* __restrict__ B, int N) {
  __shared__ float xs[32 * XS_S];
  __shared__ float ws[32 * 64];
  const int t = threadIdx.x;

  // bijective chunked XCD swizzle (nb need not be %8==0)
  const int nbk = gridDim.x;
  const int q = nbk >> 3, r = nbk & 7;
  const int xcd = blockIdx.x & 7, bidx = blockIdx.x >> 3;
  const int nw = (xcd < r ? xcd * (q + 1) : r * (q + 1) + (xcd - r) * q) + bidx;
  const int n0 = (nw >> 2) * 128;
  const int j0 = (nw & 3) * 64;  // concat col base: 0,64 -> A ; 128,192 -> B
  const bool isA = j0 < 128;
  const float* Wbase = W1 + (isA ? j0 : 128 * HID + (j0 - 128));
  float* Obase = isA ? (A + j0) : (B + (j0 - 128));

  const int tn = t & 31;  // node group: nodes tn*4 .. tn*4+3
  const int tc = t >> 5;  // col group:  cols  tc*8 .. tc*8+7

  float acc[4][8];
#pragma unroll
  for (int rr = 0; rr < 4; ++rr)
#pragma unroll
    for (int c = 0; c < 8; ++c) acc[rr][c] = 0.f;

  const int ln = t >> 3;       // staging node 0..31 (+rep*32)
  const int lf = (t & 7) * 4;  // staging k-local float4 base

  for (int kc = 0; kc < 4; ++kc) {
    __syncthreads();
    // stage X chunk transposed: xs[k_local][node]
#pragma unroll
    for (int rep = 0; rep < 4; ++rep) {
      const int nl = ln + rep * 32;
      const int n = n0 + nl;
      float4 v = make_float4(0.f, 0.f, 0.f, 0.f);
      if (n < N) v = *(const float4*)(X + (size_t)n * FEAT + kc * 32 + lf);
      xs[(lf + 0) * XS_S + nl] = v.x;
      xs[(lf + 1) * XS_S + nl] = v.y;
      xs[(lf + 2) * XS_S + nl] = v.z;
      xs[(lf + 3) * XS_S + nl] = v.w;
    }
    // stage W chunk: ws[k_local][col]
#pragma unroll
    for (int rep = 0; rep < 2; ++rep) {
      const int idx = rep * 256 + t;   // 0..511 float4s
      const int wr = idx >> 4;         // 0..31
      const int c4 = (idx & 15) * 4;   // 0..60
      *(float4*)&ws[wr * 64 + c4] =
          *(const float4*)(Wbase + (size_t)(kc * 32 + wr) * HID + c4);
    }
    __syncthreads();

#pragma unroll 8
    for (int k = 0; k < 32; ++k) {
      const float4 xv = *(const float4*)&xs[k * XS_S + tn * 4];
      const float4 w0 = *(const float4*)&ws[k * 64 + tc * 8];
      const float4 w1 = *(const float4*)&ws[k * 64 + tc * 8 + 4];
      const float xr[4] = {xv.x, xv.y, xv.z, xv.w};
#pragma unroll
      for (int rr = 0; rr < 4; ++rr) {
        acc[rr][0] = fmaf(xr[rr], w0.x, acc[rr][0]);
        acc[rr][1] = fmaf(xr[rr], w0.y, acc[rr][1]);
        acc[rr][2] = fmaf(xr[rr], w0.z, acc[rr][2]);
        acc[rr][3] = fmaf(xr[rr], w0.w, acc[rr][3]);
        acc[rr][4] = fmaf(xr[rr], w1.x, acc[rr][4]);
        acc[rr][5] = fmaf(xr[rr], w1.y, acc[rr][5]);
        acc[rr][6] = fmaf(xr[rr], w1.z, acc[rr][6]);
        acc[rr][7] = fmaf(xr[rr], w1.w, acc[rr][7]);
      }
    }
  }

  // epilogue: fold b1 into the A-half so the fused kernel needn't read it
  float bb[8];
#pragma unroll
  for (int c = 0; c < 8; ++c) bb[c] = 0.f;
  if (isA) {
    *(float4*)&bb[0] = *(const float4*)(b1 + j0 + tc * 8);
    *(float4*)&bb[4] = *(const float4*)(b1 + j0 + tc * 8 + 4);
  }
#pragma unroll
  for (int rr = 0; rr < 4; ++rr) {
    const int n = n0 + tn * 4 + rr;
    if (n < N) {
      float* o = Obase + (size_t)n * HID + tc * 8;
      *(float4*)o = make_float4(acc[rr][0] + bb[0], acc[rr][1] + bb[1],
                                acc[rr][2] + bb[2], acc[rr][3] + bb[3]);
      *(float4*)(o + 4) = make_float4(acc[rr][4] + bb[4], acc[rr][5] + bb[5],
                                      acc[rr][6] + bb[6], acc[rr][7] + bb[7]);
    }
  }
}

// ---------------------------------------------------------------------------
// Kernel 2: FUSED row_offsets + edge_z + seg_sample. One block = 16 nodes.
// R0-R5 evidence: dispatch sum <= ~176us but total ~241us -> ~15us/launch
// overhead; fusing 3 launches into 1 also kills the z (6 MB) and rs global
// roundtrips and the duplicate dst read.
//  phase 0: 17 binary searches -> CSR slice rsl[0..16] in LDS.
//  phase 0.5: stage block's src/dst (<=MAXE) into LDS.
//  phase 1: edge_z on the block's contiguous edge range -> zs[] in LDS
//           (identical math/gather shape as the proven edge_z kernel).
//  phase 2: seg_sample (unchanged logic) reading zs/dsts/rsl from LDS.
// All __syncthreads are block-uniform (cnt is uniform); LDS 24.6 KB ->
// 6 blocks/CU = 24 waves/CU.
// ---------------------------------------------------------------------------
__global__ __launch_bounds__(256) void fused_edge_seg(
    const float* __restrict__ A, const float* __restrict__ B,
    const float* __restrict__ W2, const float* __restrict__ b2,
    const int* __restrict__ src, const int* __restrict__ dst,
    const float* __restrict__ U, float* __restrict__ out_sel,
    float* __restrict__ out_soft, int N, int E, int K) {
  __shared__ float zs[MAXE];
  __shared__ int srcs[MAXE];
  __shared__ int dsts[MAXE];
  __shared__ int rsl[17];
  const int t = threadIdx.x;
  const int n0 = blockIdx.x * 16;
  const float INVTAU = 1.0f / 0.9991f;

  // ---- phase 0: CSR offsets for nodes n0..n0+16 ----
  if (t < 17) {
    const int n = min(n0 + t, N);
    int lo = 0, hi = E;
    while (lo < hi) {
      const int mid = (lo + hi) >> 1;
      if (src[mid] < n) lo = mid + 1; else hi = mid;
    }
    rsl[t] = lo;
  }
  __syncthreads();
  const int e_lo = rsl[0];
  // defensive clamp: unreachable for this data (cnt ~ Poisson(256)), but
  // guarantees no LDS scribble even on pathological inputs.
  const int cnt = min(rsl[16] - e_lo, MAXE);

  // ---- phase 0.5: stage indices ----
  for (int i = t; i < cnt; i += 256) {
    srcs[i] = src[e_lo + i];
    dsts[i] = dst[e_lo + i];
  }
  __syncthreads();

  // ---- phase 1: z for the block's edges -> zs ----
  {
    const int g = t >> 4;
    const int l = t & 15;
    const float4 w0 = *(const float4*)(W2 + l * 8);
    const float4 w1 = *(const float4*)(W2 + l * 8 + 4);
    const float bias2 = b2[0];
    for (int base = 0; base < cnt; base += 32) {
      const int i0 = base + g * 2;
      if (i0 < cnt) {
        const int i1 = i0 + 1;
        const bool has1 = i1 < cnt;
        const int u0 = srcs[i0], v0 = dsts[i0];
        const int u1 = has1 ? srcs[i1] : u0;
        const int v1 = has1 ? dsts[i1] : v0;

        const float4* Au0 = (const float4*)(A + (size_t)u0 * HID) + l * 2;
        const float4* Bv0 = (const float4*)(B + (size_t)v0 * HID) + l * 2;
        const float4* Au1 = (const float4*)(A + (size_t)u1 * HID) + l * 2;
        const float4* Bv1 = (const float4*)(B + (size_t)v1 * HID) + l * 2;

        const float4 a00 = Au0[0], a01 = Au0[1];
        const float4 b00 = Bv0[0], b01 = Bv0[1];
        const float4 a10 = Au1[0], a11 = Au1[1];
        const float4 b10 = Bv1[0], b11 = Bv1[1];

        float p0 = fmaxf(a00.x + b00.x, 0.f) * w0.x
                 + fmaxf(a00.y + b00.y, 0.f) * w0.y
                 + fmaxf(a00.z + b00.z, 0.f) * w0.z
                 + fmaxf(a00.w + b00.w, 0.f) * w0.w
                 + fmaxf(a01.x + b01.x, 0.f) * w1.x
                 + fmaxf(a01.y + b01.y, 0.f) * w1.y
                 + fmaxf(a01.z + b01.z, 0.f) * w1.z
                 + fmaxf(a01.w + b01.w, 0.f) * w1.w;
        float p1 = fmaxf(a10.x + b10.x, 0.f) * w0.x
                 + fmaxf(a10.y + b10.y, 0.f) * w0.y
                 + fmaxf(a10.z + b10.z, 0.f) * w0.z
                 + fmaxf(a10.w + b10.w, 0.f) * w0.w
                 + fmaxf(a11.x + b11.x, 0.f) * w1.x
                 + fmaxf(a11.y + b11.y, 0.f) * w1.y
                 + fmaxf(a11.z + b11.z, 0.f) * w1.z
                 + fmaxf(a11.w + b11.w, 0.f) * w1.w;

#pragma unroll
        for (int m = 8; m >= 1; m >>= 1) {
          p0 += __shfl_xor(p0, m);
          p1 += __shfl_xor(p1, m);
        }
        if (l == 0) {
          zs[i0] = p0 + bias2;
          if (has1) zs[i1] = p1 + bias2;
        }
      }
    }
  }
  __syncthreads();

  // ---- phase 2: per-node log-softmax + K Gumbel rounds (seg_sample) ----
  const int lane = t & 63;
  const int qtr = lane >> 4;   // quarter 0..3: one node each
  const int ql = lane & 15;    // lane within node: edges 2*ql, 2*ql+1
  const int li = (t >> 6) * 4 + qtr;  // local node 0..15
  const int n = n0 + li;

  int start = 0, deg = 0;
  if (n < N) { start = rsl[li]; deg = rsl[li + 1] - start; }

  if (__all(deg <= 32)) {
    // ---- fast path: 16-lane quarter per node, 2 edges/lane ----
    if (n >= N) return;
    if (deg == 0) {
      if (ql == 0)
        for (int k = 0; k < K; ++k) out_sel[(size_t)k * N + n] = -2147483648.0f;
      return;
    }
    const bool a0 = 2 * ql < deg;
    const bool a1 = 2 * ql + 1 < deg;
    const int le0 = start - e_lo + 2 * ql;  // local edge idx
    const int le1 = le0 + 1;
    const int e0 = start + 2 * ql;          // global edge idx (U / out_soft)
    const int e1 = e0 + 1;
    const float z0 = a0 ? zs[le0] : -INFINITY;
    const float z1 = a1 ? zs[le1] : -INFINITY;
    const int d0 = a0 ? dsts[le0] : -1;
    const int d1 = a1 ? dsts[le1] : -1;

    float zmax = fmaxf(z0, z1);
#pragma unroll
    for (int m = 8; m >= 1; m >>= 1) zmax = fmaxf(zmax, __shfl_xor(zmax, m));
    float den = (a0 ? __expf(z0 - zmax) : 0.f) + (a1 ? __expf(z1 - zmax) : 0.f);
#pragma unroll
    for (int m = 8; m >= 1; m >>= 1) den += __shfl_xor(den, m);
    const float logd = __logf(den);
    const float lp0 = (z0 - zmax) - logd;  // per-edge log-prob
    const float lp1 = (z1 - zmax) - logd;

    for (int k = 0; k < K; ++k) {
      float ex0 = 0.f, ex1 = 0.f;
      if (a0) {
        const float uu = U[(size_t)k * E + e0];
        const float gum = -__logf(-__logf(uu));
        ex0 = __expf((lp0 + gum) * INVTAU);  // exp(s); s in [-19,15] -> safe
      }
      if (a1) {
        const float uu = U[(size_t)k * E + e1];
        const float gum = -__logf(-__logf(uu));
        ex1 = __expf((lp1 + gum) * INVTAU);
      }
      // lane-local pair combine (tie -> larger dst, matching reference)
      float d2 = ex0 + ex1;
      float mx;
      int md;
      if (ex1 > ex0)      { mx = ex1; md = d1; }
      else if (ex1 < ex0) { mx = ex0; md = d0; }
      else                { mx = ex0; md = max(d0, d1); }
#pragma unroll
      for (int m = 8; m >= 1; m >>= 1) {
        d2 += __shfl_xor(d2, m);
        const float ox = __shfl_xor(mx, m);
        const int od = __shfl_xor(md, m);
        if (ox > mx) { mx = ox; md = od; }
        else if (ox == mx) md = max(md, od);
      }
      if (ql == 0) out_sel[(size_t)k * N + n] = (float)md;
      const float inv = __builtin_amdgcn_rcpf(d2);
      if (a0) out_soft[(size_t)k * E + e0] = ex0 * inv;
      if (a1) out_soft[(size_t)k * E + e1] = ex1 * inv;
    }
    return;
  }

  // ---- general path (some deg > 32, ~5 nodes chip-wide): full wave/node ----
  const int lbase = (t >> 6) * 4;
  for (int j = 0; j < 4; ++j) {
    const int lj = lbase + j;
    const int nn = n0 + lj;
    if (nn >= N) continue;
    const int st = rsl[lj];
    const int dg = rsl[lj + 1] - st;
    const int lst = st - e_lo;
    if (dg == 0) {
      if (lane == 0)
        for (int k = 0; k < K; ++k) out_sel[(size_t)k * N + nn] = -2147483648.0f;
      continue;
    }
    float zmax = -INFINITY;
    for (int c = lane; c < dg; c += 64) zmax = fmaxf(zmax, zs[lst + c]);
#pragma unroll
    for (int m = 32; m >= 1; m >>= 1) zmax = fmaxf(zmax, __shfl_xor(zmax, m));
    float den = 0.f;
    for (int c = lane; c < dg; c += 64) den += expf(zs[lst + c] - zmax);
#pragma unroll
    for (int m = 32; m >= 1; m >>= 1) den += __shfl_xor(den, m);
    const float logd = logf(den);

    for (int k = 0; k < K; ++k) {
      float m2 = -INFINITY;
      for (int c = lane; c < dg; c += 64) {
        const float gum = -logf(-logf(U[(size_t)k * E + st + c]));
        const float s = ((zs[lst + c] - zmax) - logd + gum) * INVTAU;
        m2 = fmaxf(m2, s);
      }
#pragma unroll
      for (int m = 32; m >= 1; m >>= 1) m2 = fmaxf(m2, __shfl_xor(m2, m));
      float d2 = 0.f;
      int cand = -1;
      for (int c = lane; c < dg; c += 64) {
        const float gum = -logf(-logf(U[(size_t)k * E + st + c]));
        const float s = ((zs[lst + c] - zmax) - logd + gum) * INVTAU;
        d2 += expf(s - m2);
        if (s >= m2) cand = max(cand, dsts[lst + c]);
      }
#pragma unroll
      for (int m = 32; m >= 1; m >>= 1) d2 += __shfl_xor(d2, m);
#pragma unroll
      for (int m = 32; m >= 1; m >>= 1) cand = max(cand, __shfl_xor(cand, m));
      if (lane == 0) out_sel[(size_t)k * N + nn] = (float)cand;
      for (int c = lane; c < dg; c += 64) {
        const float gum = -logf(-logf(U[(size_t)k * E + st + c]));
        const float s = ((zs[lst + c] - zmax) - logd + gum) * INVTAU;
        out_soft[(size_t)k * E + st + c] = expf(s - m2) / d2;
      }
    }
  }
}

// ---------------------------------------------------------------------------
extern "C" void kernel_launch(void* const* d_in, const int* in_sizes, int n_in,
                              void* d_out, int out_size, void* d_ws, size_t ws_size,
                              hipStream_t stream) {
  const float* X  = (const float*)d_in[0];  // (N, 128)
  const float* W1 = (const float*)d_in[1];  // (256, 128)
  const float* b1 = (const float*)d_in[2];  // (128,)
  const float* W2 = (const float*)d_in[3];  // (128,)
  const float* b2 = (const float*)d_in[4];  // (1,)
  const float* U  = (const float*)d_in[5];  // (K, E)
  const int* src  = (const int*)d_in[6];    // (E,) sorted
  const int* dst  = (const int*)d_in[7];    // (E,)
  const int E = in_sizes[6];
  const int K = in_sizes[5] / E;
  const int N = in_sizes[0] / FEAT;

  // workspace: A (N*128 f32) | B (N*128 f32)
  float* A = (float*)d_ws;
  float* B = A + (size_t)N * HID;

  float* out_sel  = (float*)d_out;                  // (K, N) as f32
  float* out_soft = (float*)d_out + (size_t)K * N;  // (K, E)

  hipLaunchKernelGGL(gemm_ab, dim3(4 * ((N + 127) / 128)), dim3(256), 0, stream,
                     X, W1, b1, A, B, N);
  hipLaunchKernelGGL(fused_edge_seg, dim3((N + 15) / 16), dim3(256), 0, stream,
                     A, B, W2, b2, src, dst, U, out_sel, out_soft, N, E, K);
}